// Round 13
// baseline (89.321 us; speedup 1.0000x reference)
//
#include <hip/hip_runtime.h>
#include <hip/hip_bf16.h>
#include <stdint.h>

typedef __attribute__((ext_vector_type(8))) short bf16x8;
typedef __attribute__((ext_vector_type(4))) float f32x4;
typedef __attribute__((ext_vector_type(16))) float f32x16;

#define S_LEN 2048
#define D_DIM 128
#define HQ_N  32
#define NT32  64            // 32-row kv subtiles per kv-head
#define SUB_B 8192          // 32-row subtile bytes (512 chunks x 16B)

__device__ __forceinline__ ushort f2bf(float f) {
  union { float f; uint32_t u; } c; c.f = f;
  uint32_t u = c.u;
  u += 0x7FFFu + ((u >> 16) & 1u);   // round-nearest-even
  return (ushort)(u >> 16);
}

__device__ __forceinline__ uint32_t cvtpk(float lo, float hi) {
  uint32_t r;
  asm("v_cvt_pk_bf16_f32 %0, %1, %2" : "=v"(r) : "v"(lo), "v"(hi));
  return r;
}

// cross-half (lane^32) max via permlane32_swap, VALU-only (validated R9-R12)
__device__ __forceinline__ float xhalf_max(float x) {
  uint32_t a = __builtin_bit_cast(uint32_t, x), b;
  asm volatile("v_mov_b32 %0, %1" : "=&v"(b) : "v"(a));
  asm volatile("v_permlane32_swap_b32 %0, %1" : "+v"(a), "+v"(b));
  return fmaxf(__builtin_bit_cast(float, a), __builtin_bit_cast(float, b));
}

// ---- prep K: fragment-ordered bf16 subtiles (layout unchanged R7-R12) ----
__global__ __launch_bounds__(256) void prep_k(const float* __restrict__ K,
                                              ushort* __restrict__ KT) {
  int tid  = blockIdx.x * 256 + threadIdx.x;   // 262144
  int tile = tid >> 9;
  int c    = tid & 511;
  int s    = c >> 6;
  int lane = c & 63;
  int l31  = lane & 31, hi = lane >> 5;
  const float* src = K + ((size_t)(tile * 32 + l31)) * D_DIM + 16 * s + 8 * hi;
  float4 x = *(const float4*)src;
  float4 y = *(const float4*)(src + 4);
  union { ushort u[8]; bf16x8 v; } o;
  o.u[0] = f2bf(x.x); o.u[1] = f2bf(x.y); o.u[2] = f2bf(x.z); o.u[3] = f2bf(x.w);
  o.u[4] = f2bf(y.x); o.u[5] = f2bf(y.y); o.u[6] = f2bf(y.z); o.u[7] = f2bf(y.w);
  *(bf16x8*)(KT + (size_t)tid * 8) = o.v;
}

// ---- prep V: fragment-ordered transposed subtiles (unchanged R7-R12) ----
__global__ __launch_bounds__(256) void prep_v(const float* __restrict__ V,
                                              ushort* __restrict__ VT) {
  int tid  = blockIdx.x * 256 + threadIdx.x;   // 262144
  int tile = tid >> 9;
  int cc   = tid & 511;
  int l31  = cc & 31;
  int hi   = (cc >> 5) & 1;
  int c    = (cc >> 6) & 1;
  int dt   = cc >> 7;
  int hkv  = tile >> 6, ktv = tile & 63;
  const float* src = V + ((size_t)hkv * S_LEN + ktv * 32 + 16 * c + 8 * hi) * D_DIM
                       + 32 * dt + l31;
  union { ushort u[8]; bf16x8 v; } o;
  #pragma unroll
  for (int jj = 0; jj < 8; ++jj) o.u[jj] = f2bf(src[(size_t)jj * D_DIM]);
  *(bf16x8*)(VT + (size_t)tid * 8) = o.v;
}

// ---- one pipelined step: issue tile kt+1 loads around tile kt compute ----
// sched_barrier(0) fences pin the issue order so the allocator must keep the
// next tile's fragments live -> loads stay outstanding across the whole step.
__device__ __forceinline__ void step_pipe(
    int kt, int j, int qrow, int hi, int lane,
    const char* kt_base, const char* vt_base,
    const bf16x8 (&qf)[8],
    bf16x8 (&KC)[8], bf16x8 (&VC)[8],     // current tile (loaded last step)
    bf16x8 (&KN)[8], bf16x8 (&VN)[8],     // next tile (filled here)
    const bf16x8& ones, const f32x16& zero16,
    f32x16 (&o4)[4], float& mrow, float& lsum) {
  // 1. issue next-tile K loads
  if (kt < j) {
    const char* kp2 = kt_base + (size_t)(kt + 1) * SUB_B;
    #pragma unroll
    for (int s = 0; s < 8; ++s)
      KN[s] = *(const bf16x8*)(kp2 + (s * 64 + lane) * 16);
  }
  __builtin_amdgcn_sched_barrier(0);

  // 2. QK^T on current K (in registers since last step)
  f32x16 st = {};
  __builtin_amdgcn_s_setprio(1);
  #pragma unroll
  for (int s = 0; s < 8; ++s)
    st = __builtin_amdgcn_mfma_f32_32x32x16_bf16(KC[s], qf[s], st, 0, 0, 0);
  __builtin_amdgcn_s_setprio(0);
  __builtin_amdgcn_sched_barrier(0);

  // 3. issue next-tile V loads (land during next step's QK^T/softmax)
  if (kt < j) {
    const char* vp2 = vt_base + (size_t)(kt + 1) * SUB_B;
    #pragma unroll
    for (int u = 0; u < 8; ++u)
      VN[u] = *(const bf16x8*)(vp2 + (u * 64 + lane) * 16);
  }
  __builtin_amdgcn_sched_barrier(0);

  // 4. causal mask (diagonal tile only)
  if (kt == j) {
    #pragma unroll
    for (int r = 0; r < 16; ++r) {
      int kv = 32 * kt + (r & 3) + 8 * (r >> 2) + 4 * hi;
      if (kv > qrow) st[r] = -1e30f;
    }
  }

  // 5. online softmax (lane-local rows, validated R9)
  float t8[8];
  #pragma unroll
  for (int e = 0; e < 8; ++e) t8[e] = fmaxf(st[e], st[e + 8]);
  float mx = fmaxf(fmaxf(fmaxf(t8[0], t8[1]), fmaxf(t8[2], t8[3])),
                   fmaxf(fmaxf(t8[4], t8[5]), fmaxf(t8[6], t8[7])));
  mx = xhalf_max(mx);
  if (!__all(mx <= mrow + 8.0f)) {       // defer-max (T13)
    float mnew = fmaxf(mrow, mx);
    float alpha = exp2f(mrow - mnew);
    #pragma unroll
    for (int dt = 0; dt < 4; ++dt) o4[dt] *= alpha;
    lsum *= alpha;
    mrow = mnew;
  }
  #pragma unroll
  for (int e = 0; e < 16; ++e) st[e] = exp2f(st[e] - mrow);

  // 6. pack P^T (validated recipe)
  bf16x8 pb[2];
  #pragma unroll
  for (int c = 0; c < 2; ++c) {
    const int r0 = c * 8;
    uint32_t a0 = cvtpk(st[r0 + 0], st[r0 + 1]);
    uint32_t b0 = cvtpk(st[r0 + 4], st[r0 + 5]);
    asm volatile("v_permlane32_swap_b32 %0, %1" : "+v"(a0), "+v"(b0));
    uint32_t a1 = cvtpk(st[r0 + 2], st[r0 + 3]);
    uint32_t b1 = cvtpk(st[r0 + 6], st[r0 + 7]);
    asm volatile("v_permlane32_swap_b32 %0, %1" : "+v"(a1), "+v"(b1));
    union { uint32_t u[4]; bf16x8 v; } pu;
    pu.u[0] = a0; pu.u[1] = a1; pu.u[2] = b0; pu.u[3] = b1;
    pb[c] = pu.v;
  }

  // 7. row-sum of P via ones-MFMA + PV on current V
  f32x16 pbsum = __builtin_amdgcn_mfma_f32_32x32x16_bf16(ones, pb[0], zero16, 0, 0, 0);
  pbsum = __builtin_amdgcn_mfma_f32_32x32x16_bf16(ones, pb[1], pbsum, 0, 0, 0);
  __builtin_amdgcn_s_setprio(1);
  #pragma unroll
  for (int dt = 0; dt < 4; ++dt) {
    o4[dt] = __builtin_amdgcn_mfma_f32_32x32x16_bf16(VC[2 * dt + 0], pb[0], o4[dt], 0, 0, 0);
    o4[dt] = __builtin_amdgcn_mfma_f32_32x32x16_bf16(VC[2 * dt + 1], pb[1], o4[dt], 0, 0, 0);
  }
  __builtin_amdgcn_s_setprio(0);
  lsum += pbsum[0];
}

// ---- flash attention: 1-wave blocks, quad-lockstep map, enforced pipeline ----
__global__ __launch_bounds__(64, 2) void attn_fwd(
    const float* __restrict__ Q, const ushort* __restrict__ KT,
    const ushort* __restrict__ VT, float* __restrict__ O) {
  const int id   = blockIdx.x;           // 2048 blocks
  // R11-validated mapping: XCD = id%8 (= kv-head), CU slot = (id>>3)%32,
  // rounds stack 4 q-heads x {j=c, 63-c} on one CU (lockstep KV streams).
  const int g    = id & 7;
  const int c    = (id >> 3) & 31;
  const int qh   = (id >> 8) & 3;
  const int p    = (id >> 10) & 1;
  const int j    = p ? (63 - c) : c;     // q-tile (32 rows)
  const int h    = g * 4 + qh;
  const int lane = threadIdx.x;
  const int l31  = lane & 31;
  const int hi   = lane >> 5;
  const int qrow = j * 32 + l31;

  const char* kt_base = (const char*)KT + (size_t)g * NT32 * SUB_B;
  const char* vt_base = (const char*)VT + (size_t)g * NT32 * SUB_B;

  // Q fragments (B operand), log2-domain scale
  const float scale = 0.08838834764831845f * 1.4426950408889634f;
  bf16x8 qf[8];
  {
    const float* qp = Q + ((size_t)h * S_LEN + qrow) * D_DIM;
    #pragma unroll
    for (int s = 0; s < 8; ++s) {
      const float* px = qp + 16 * s + 8 * hi;
      float4 x = *(const float4*)px;
      float4 y = *(const float4*)(px + 4);
      bf16x8 f;
      f[0] = (short)f2bf(x.x * scale); f[1] = (short)f2bf(x.y * scale);
      f[2] = (short)f2bf(x.z * scale); f[3] = (short)f2bf(x.w * scale);
      f[4] = (short)f2bf(y.x * scale); f[5] = (short)f2bf(y.y * scale);
      f[6] = (short)f2bf(y.z * scale); f[7] = (short)f2bf(y.w * scale);
      qf[s] = f;
    }
  }

  bf16x8 ones;
  #pragma unroll
  for (int s = 0; s < 8; ++s) ones[s] = (short)0x3F80;   // bf16 1.0
  const f32x16 zero16 = {};

  f32x16 o4[4] = {};       // O^T: q=l31, d = 32*dt + (r&3)+8*(r>>2)+4*hi
  float mrow = -1e30f, lsum = 0.f;

  // prologue: load tile 0 into set A
  bf16x8 KA[8], VA[8], KB[8], VB[8];
  #pragma unroll
  for (int s = 0; s < 8; ++s)
    KA[s] = *(const bf16x8*)(kt_base + (s * 64 + lane) * 16);
  #pragma unroll
  for (int u = 0; u < 8; ++u)
    VA[u] = *(const bf16x8*)(vt_base + (u * 64 + lane) * 16);

  // manual 2x unroll keeps both register sets statically indexed
  int kt = 0;
  for (;;) {
    step_pipe(kt, j, qrow, hi, lane, kt_base, vt_base, qf, KA, VA, KB, VB,
              ones, zero16, o4, mrow, lsum);
    if (++kt > j) break;
    step_pipe(kt, j, qrow, hi, lane, kt_base, vt_base, qf, KB, VB, KA, VA,
              ones, zero16, o4, mrow, lsum);
    if (++kt > j) break;
  }

  // ---- epilogue ----
  const float inv = 1.0f / lsum;
  float* op = O + ((size_t)h * S_LEN + qrow) * D_DIM;
  #pragma unroll
  for (int dt = 0; dt < 4; ++dt)
    #pragma unroll
    for (int rq = 0; rq < 4; ++rq) {
      f32x4 vv;
      #pragma unroll
      for (int jj = 0; jj < 4; ++jj) vv[jj] = o4[dt][rq * 4 + jj] * inv;
      *(f32x4*)(op + 32 * dt + 8 * rq + 4 * hi) = vv;
    }
}

extern "C" void kernel_launch(void* const* d_in, const int* in_sizes, int n_in,
                              void* d_out, int out_size, void* d_ws, size_t ws_size,
                              hipStream_t stream) {
  const float* Q = (const float*)d_in[0];
  const float* K = (const float*)d_in[1];
  const float* V = (const float*)d_in[2];
  float* O = (float*)d_out;
  ushort* wsK = (ushort*)d_ws;
  ushort* wsV = wsK + (size_t)8 * NT32 * (SUB_B / 2);   // +4MB
  prep_k<<<1024, 256, 0, stream>>>(K, wsK);
  prep_v<<<1024, 256, 0, stream>>>(V, wsV);
  attn_fwd<<<2048, 64, 0, stream>>>(Q, wsK, wsV, O);
}

// Round 14
// 75.173 us; speedup vs baseline: 1.1882x; 1.1882x over previous
//
#include <hip/hip_runtime.h>
#include <hip/hip_bf16.h>
#include <stdint.h>

typedef __attribute__((ext_vector_type(8))) short bf16x8;
typedef __attribute__((ext_vector_type(4))) float f32x4;
typedef __attribute__((ext_vector_type(16))) float f32x16;

#define S_LEN 2048
#define D_DIM 128
#define HQ_N  32
#define NT32  64            // 32-row kv subtiles per kv-head
#define SUB_B 8192          // 32-row subtile bytes (512 chunks x 16B)

__device__ __forceinline__ ushort f2bf(float f) {
  union { float f; uint32_t u; } c; c.f = f;
  uint32_t u = c.u;
  u += 0x7FFFu + ((u >> 16) & 1u);   // round-nearest-even
  return (ushort)(u >> 16);
}

__device__ __forceinline__ uint32_t cvtpk(float lo, float hi) {
  uint32_t r;
  asm("v_cvt_pk_bf16_f32 %0, %1, %2" : "=v"(r) : "v"(lo), "v"(hi));
  return r;
}

// cross-half (lane^32) max via permlane32_swap, VALU-only (validated R9-R13)
__device__ __forceinline__ float xhalf_max(float x) {
  uint32_t a = __builtin_bit_cast(uint32_t, x), b;
  asm volatile("v_mov_b32 %0, %1" : "=&v"(b) : "v"(a));
  asm volatile("v_permlane32_swap_b32 %0, %1" : "+v"(a), "+v"(b));
  return fmaxf(__builtin_bit_cast(float, a), __builtin_bit_cast(float, b));
}

// ---- prep K: fragment-ordered bf16 subtiles (layout unchanged R7-R13) ----
__global__ __launch_bounds__(256) void prep_k(const float* __restrict__ K,
                                              ushort* __restrict__ KT) {
  int tid  = blockIdx.x * 256 + threadIdx.x;   // 262144
  int tile = tid >> 9;
  int c    = tid & 511;
  int s    = c >> 6;
  int lane = c & 63;
  int l31  = lane & 31, hi = lane >> 5;
  const float* src = K + ((size_t)(tile * 32 + l31)) * D_DIM + 16 * s + 8 * hi;
  float4 x = *(const float4*)src;
  float4 y = *(const float4*)(src + 4);
  union { ushort u[8]; bf16x8 v; } o;
  o.u[0] = f2bf(x.x); o.u[1] = f2bf(x.y); o.u[2] = f2bf(x.z); o.u[3] = f2bf(x.w);
  o.u[4] = f2bf(y.x); o.u[5] = f2bf(y.y); o.u[6] = f2bf(y.z); o.u[7] = f2bf(y.w);
  *(bf16x8*)(KT + (size_t)tid * 8) = o.v;
}

// ---- prep V: fragment-ordered transposed subtiles (unchanged R7-R13) ----
__global__ __launch_bounds__(256) void prep_v(const float* __restrict__ V,
                                              ushort* __restrict__ VT) {
  int tid  = blockIdx.x * 256 + threadIdx.x;   // 262144
  int tile = tid >> 9;
  int cc   = tid & 511;
  int l31  = cc & 31;
  int hi   = (cc >> 5) & 1;
  int c    = (cc >> 6) & 1;
  int dt   = cc >> 7;
  int hkv  = tile >> 6, ktv = tile & 63;
  const float* src = V + ((size_t)hkv * S_LEN + ktv * 32 + 16 * c + 8 * hi) * D_DIM
                       + 32 * dt + l31;
  union { ushort u[8]; bf16x8 v; } o;
  #pragma unroll
  for (int jj = 0; jj < 8; ++jj) o.u[jj] = f2bf(src[(size_t)jj * D_DIM]);
  *(bf16x8*)(VT + (size_t)tid * 8) = o.v;
}

// ---- flash attention: fused free-running quad (4 waves = 4 q-heads, NO barriers) ----
__global__ __launch_bounds__(256, 2) void attn_fwd(
    const float* __restrict__ Q, const ushort* __restrict__ KT,
    const ushort* __restrict__ VT, float* __restrict__ O) {
  const int id   = blockIdx.x;           // 512 blocks
  // Dispatch model (validated R11/R12): XCD = id%8, CU slot = (id>>3)%32.
  // Block = 4 waves = 4 q-heads of kv-head g at the same q-tile j: identical KV
  // streams -> lead wave fills L1, trailing waves hit. NO barrier: waves free-run
  // and self-stagger, so fills are pipelined instead of lockstep-stalled (R12 bug).
  const int g    = id & 7;               // kv-head == XCD
  const int c    = (id >> 3) & 31;       // CU slot
  const int p    = (id >> 8) & 1;
  const int j    = p ? (63 - c) : c;     // q-tile (32 rows)
  const int qh   = threadIdx.x >> 6;     // wave = q-head within group
  const int h    = g * 4 + qh;
  const int lane = threadIdx.x & 63;
  const int l31  = lane & 31;
  const int hi   = lane >> 5;
  const int qrow = j * 32 + l31;
  const int jt   = j >> 1;               // last 64-row kv tile index

  const char* kt_base = (const char*)KT + (size_t)g * NT32 * SUB_B;
  const char* vt_base = (const char*)VT + (size_t)g * NT32 * SUB_B;

  // Q fragments (B operand), log2-domain scale
  const float scale = 0.08838834764831845f * 1.4426950408889634f;
  bf16x8 qf[8];
  {
    const float* qp = Q + ((size_t)h * S_LEN + qrow) * D_DIM;
    #pragma unroll
    for (int s = 0; s < 8; ++s) {
      const float* px = qp + 16 * s + 8 * hi;
      float4 x = *(const float4*)px;
      float4 y = *(const float4*)(px + 4);
      bf16x8 f;
      f[0] = (short)f2bf(x.x * scale); f[1] = (short)f2bf(x.y * scale);
      f[2] = (short)f2bf(x.z * scale); f[3] = (short)f2bf(x.w * scale);
      f[4] = (short)f2bf(y.x * scale); f[5] = (short)f2bf(y.y * scale);
      f[6] = (short)f2bf(y.z * scale); f[7] = (short)f2bf(y.w * scale);
      qf[s] = f;
    }
  }

  bf16x8 ones;
  #pragma unroll
  for (int s = 0; s < 8; ++s) ones[s] = (short)0x3F80;   // bf16 1.0
  const f32x16 zero16 = {};

  f32x16 o4[4] = {};       // O^T: q=l31, d = 32*dt + (r&3)+8*(r>>2)+4*hi
  float mrow = -1e30f, lsum = 0.f;

  for (int kt = 0; kt <= jt; ++kt) {
    const char* kp = kt_base + (size_t)kt * (2 * SUB_B);

    // ---- issue K (16 frags) + V first half (8 frags); quad shares lines via L1 ----
    bf16x8 kf[16];
    #pragma unroll
    for (int t = 0; t < 2; ++t)
      #pragma unroll
      for (int s = 0; s < 8; ++s)
        kf[t * 8 + s] = *(const bf16x8*)(kp + t * SUB_B + (s * 64 + lane) * 16);
    bf16x8 vfA[8], vfB[8];
    const char* vp = vt_base + (size_t)(2 * kt) * SUB_B;
    #pragma unroll
    for (int ks = 0; ks < 2; ++ks)
      #pragma unroll
      for (int dt = 0; dt < 4; ++dt)
        vfA[ks * 4 + dt] = *(const bf16x8*)(vp + (dt * 128 + ks * 64 + lane) * 16);

    // ---- S^T = K Q (2 kv-subtiles) ----
    f32x16 st[2] = {};
    __builtin_amdgcn_s_setprio(1);
    #pragma unroll
    for (int t = 0; t < 2; ++t)
      #pragma unroll
      for (int s = 0; s < 8; ++s)
        st[t] = __builtin_amdgcn_mfma_f32_32x32x16_bf16(kf[t * 8 + s], qf[s], st[t], 0, 0, 0);
    __builtin_amdgcn_s_setprio(0);

    // ---- issue V second half; lands during softmax ----
    #pragma unroll
    for (int ks = 0; ks < 2; ++ks)
      #pragma unroll
      for (int dt = 0; dt < 4; ++dt)
        vfB[ks * 4 + dt] = *(const bf16x8*)(vp + SUB_B + (dt * 128 + ks * 64 + lane) * 16);

    // ---- causal mask (diagonal 64-tile only) ----
    if (kt == jt) {
      #pragma unroll
      for (int t = 0; t < 2; ++t)
        #pragma unroll
        for (int r = 0; r < 16; ++r) {
          int kv = 64 * kt + 32 * t + (r & 3) + 8 * (r >> 2) + 4 * hi;
          if (kv > qrow) st[t][r] = -1e30f;
        }
    }

    // ---- online softmax over 32 lane-local values ----
    float t16[8];
    #pragma unroll
    for (int e = 0; e < 8; ++e)
      t16[e] = fmaxf(fmaxf(st[0][e], st[0][e + 8]), fmaxf(st[1][e], st[1][e + 8]));
    float mx = fmaxf(fmaxf(fmaxf(t16[0], t16[1]), fmaxf(t16[2], t16[3])),
                     fmaxf(fmaxf(t16[4], t16[5]), fmaxf(t16[6], t16[7])));
    mx = xhalf_max(mx);
    // defer-max (T13, validated R8-R13)
    if (!__all(mx <= mrow + 8.0f)) {
      float mnew = fmaxf(mrow, mx);
      float alpha = exp2f(mrow - mnew);
      #pragma unroll
      for (int dt = 0; dt < 4; ++dt) o4[dt] *= alpha;
      lsum *= alpha;
      mrow = mnew;
    }
    #pragma unroll
    for (int t = 0; t < 2; ++t)
      #pragma unroll
      for (int e = 0; e < 16; ++e) st[t][e] = exp2f(st[t][e] - mrow);

    // ---- pack P^T (validated recipe, per kv-subtile) ----
    bf16x8 pb[4];
    #pragma unroll
    for (int t = 0; t < 2; ++t)
      #pragma unroll
      for (int cc = 0; cc < 2; ++cc) {
        const int r0 = cc * 8;
        uint32_t a0 = cvtpk(st[t][r0 + 0], st[t][r0 + 1]);
        uint32_t b0 = cvtpk(st[t][r0 + 4], st[t][r0 + 5]);
        asm volatile("v_permlane32_swap_b32 %0, %1" : "+v"(a0), "+v"(b0));
        uint32_t a1 = cvtpk(st[t][r0 + 2], st[t][r0 + 3]);
        uint32_t b1 = cvtpk(st[t][r0 + 6], st[t][r0 + 7]);
        asm volatile("v_permlane32_swap_b32 %0, %1" : "+v"(a1), "+v"(b1));
        union { uint32_t u[4]; bf16x8 v; } pu;
        pu.u[0] = a0; pu.u[1] = a1; pu.u[2] = b0; pu.u[3] = b1;
        pb[t * 2 + cc] = pu.v;
      }

    // ---- row-sum of P via ones-MFMA ----
    f32x16 pbsum = __builtin_amdgcn_mfma_f32_32x32x16_bf16(ones, pb[0], zero16, 0, 0, 0);
    pbsum = __builtin_amdgcn_mfma_f32_32x32x16_bf16(ones, pb[1], pbsum, 0, 0, 0);
    pbsum = __builtin_amdgcn_mfma_f32_32x32x16_bf16(ones, pb[2], pbsum, 0, 0, 0);
    pbsum = __builtin_amdgcn_mfma_f32_32x32x16_bf16(ones, pb[3], pbsum, 0, 0, 0);

    // ---- O^T += V^T P^T (4 k-slices of 16) ----
    __builtin_amdgcn_s_setprio(1);
    #pragma unroll
    for (int dt = 0; dt < 4; ++dt) {
      o4[dt] = __builtin_amdgcn_mfma_f32_32x32x16_bf16(vfA[0 * 4 + dt], pb[0], o4[dt], 0, 0, 0);
      o4[dt] = __builtin_amdgcn_mfma_f32_32x32x16_bf16(vfA[1 * 4 + dt], pb[1], o4[dt], 0, 0, 0);
      o4[dt] = __builtin_amdgcn_mfma_f32_32x32x16_bf16(vfB[0 * 4 + dt], pb[2], o4[dt], 0, 0, 0);
      o4[dt] = __builtin_amdgcn_mfma_f32_32x32x16_bf16(vfB[1 * 4 + dt], pb[3], o4[dt], 0, 0, 0);
    }
    __builtin_amdgcn_s_setprio(0);

    lsum += pbsum[0];
    // no __syncthreads: waves free-run (R12's lockstep stall was the regression)
  }

  // ---- epilogue ----
  const float inv = 1.0f / lsum;
  float* op = O + ((size_t)h * S_LEN + qrow) * D_DIM;
  #pragma unroll
  for (int dt = 0; dt < 4; ++dt)
    #pragma unroll
    for (int rq = 0; rq < 4; ++rq) {
      f32x4 vv;
      #pragma unroll
      for (int jj = 0; jj < 4; ++jj) vv[jj] = o4[dt][rq * 4 + jj] * inv;
      *(f32x4*)(op + 32 * dt + 8 * rq + 4 * hi) = vv;
    }
}

extern "C" void kernel_launch(void* const* d_in, const int* in_sizes, int n_in,
                              void* d_out, int out_size, void* d_ws, size_t ws_size,
                              hipStream_t stream) {
  const float* Q = (const float*)d_in[0];
  const float* K = (const float*)d_in[1];
  const float* V = (const float*)d_in[2];
  float* O = (float*)d_out;
  ushort* wsK = (ushort*)d_ws;
  ushort* wsV = wsK + (size_t)8 * NT32 * (SUB_B / 2);   // +4MB
  prep_k<<<1024, 256, 0, stream>>>(K, wsK);
  prep_v<<<1024, 256, 0, stream>>>(V, wsV);
  attn_fwd<<<512, 256, 0, stream>>>(Q, wsK, wsV, O);
}